// Round 19
// baseline (26.955 us; speedup 1.0000x reference)
//
#include <hip/hip_runtime.h>
#include <cfloat>
#include <climits>

#define B_   8
#define N1_  1024
#define N2_  4096
#define C_   256
#define TPQ  16                 // lanes per query-group
#define QPG  2                  // queries per group (packed in vf2)
#define QPB  ((256 / TPQ) * QPG)  // 32 queries per block

typedef float vf2 __attribute__((ext_vector_type(2)));

__device__ __forceinline__ unsigned umin_(unsigned a, unsigned b) { return a < b ? a : b; }

// Guaranteed single-op median-of-3 (u32). VOP3, all-VGPR operands.
__device__ __forceinline__ unsigned umed3_(unsigned a, unsigned b, unsigned c) {
    unsigned d;
    asm("v_med3_u32 %0, %1, %2, %3" : "=v"(d) : "v"(a), "v"(b), "v"(c));
    return d;
}

// Sorted-quad insert (invariant k0<=k1<=k2<=k3): min + 3x med3 = 4 VALU ops.
#define KINS4(k, k0, k1, k2, k3) do {                 \
    unsigned _n1 = umed3_((k), k0, k1);               \
    unsigned _n2 = umed3_((k), k1, k2);               \
    unsigned _n3 = umed3_((k), k2, k3);               \
    k0 = umin_((k), k0);  k1 = _n1;  k2 = _n2;  k3 = _n3; \
} while (0)

// ---------------------------------------------------------------------------
// Kernel 1 (v14): 3-NN. Validated trunc-key top-4 + EXACT rescue
// (R9/R14/R15/R17/R18), restructured for the measured LDS wall:
// QPT=2 — each lane scans candidates for TWO queries packed in vf2, so one
// ds_read_b128 serves 2 evals (LDS bytes/eval halved; VALU/eval unchanged).
//   dd_pair = pk_max(pk_fma(-cz,z2v, pk_fma(-cy,y2v, pk_fma(-cx,x2v, s2v)))
//             + s1, 0)   [candidate splat via op_sel — free]
// Scan jitter class == R17 (validated); rescue recomputes EXACT reference
// bit-order distances, so output bits depend only on the selected set.
// ---------------------------------------------------------------------------
__global__ __launch_bounds__(256) void knn_kernel(
    const float* __restrict__ p1, const float* __restrict__ p2,
    int4* __restrict__ wsi, float4* __restrict__ wsw) {
#pragma clang fp contract(off)
    __shared__ float4 pts[N1_];   // {2x, 2y, 2z, |p1|^2}: 16 KB

    const int tid   = threadIdx.x;
    const int b     = blockIdx.x >> 7;     // 128 query-tiles per batch
    const int mtile = blockIdx.x & 127;

    // Stage coarse points (scalar layout, exact pre-doubling under RN).
    for (int j = tid; j < N1_; j += 256) {
        float x = p1[((size_t)b * N1_ + j) * 3 + 0];
        float y = p1[((size_t)b * N1_ + j) * 3 + 1];
        float z = p1[((size_t)b * N1_ + j) * 3 + 2];
        float s1 = __fadd_rn(__fadd_rn(__fmul_rn(x, x), __fmul_rn(y, y)),
                             __fmul_rn(z, z));
        pts[j] = make_float4(x + x, y + y, z + z, s1);
    }
    __syncthreads();

    const int g = tid >> 4;       // query group (0..15)
    const int t = tid & 15;       // lane within group
    const int mA = mtile * QPB + 2 * g;   // this group's two queries
    const int mB = mA + 1;

    const size_t pbA = ((size_t)b * N2_ + mA) * 3;
    const float xa = p2[pbA + 0], ya = p2[pbA + 1], za = p2[pbA + 2];
    const float xb = p2[pbA + 3], yb = p2[pbA + 4], zb = p2[pbA + 5];
    const float s2a = __fadd_rn(__fadd_rn(__fmul_rn(xa, xa), __fmul_rn(ya, ya)),
                                __fmul_rn(za, za));
    const float s2b = __fadd_rn(__fadd_rn(__fmul_rn(xb, xb), __fmul_rn(yb, yb)),
                                __fmul_rn(zb, zb));

    const vf2 x2v = {xa, xb};
    const vf2 y2v = {ya, yb};
    const vf2 z2v = {za, zb};
    const vf2 s2v = {s2a, s2b};
    const vf2 zero = {0.f, 0.f};

    unsigned a0 = UINT_MAX, a1 = UINT_MAX, a2 = UINT_MAX, a3 = UINT_MAX;  // qA
    unsigned b0 = UINT_MAX, b1 = UINT_MAX, b2 = UINT_MAX, b3 = UINT_MAX;  // qB

    // 64 candidate-iters per lane; one ds_read_b128 serves both queries.
#pragma unroll 4
    for (int j = 0; j < N1_ / TPQ; ++j) {
        const int n = t + TPQ * j;
        const float4 c = pts[n];
        const vf2 cx = {c.x, c.x};
        const vf2 cy = {c.y, c.y};
        const vf2 cz = {c.z, c.z};
        const vf2 cw = {c.w, c.w};
        vf2 t0 = __builtin_elementwise_fma(-cx, x2v, s2v);
        vf2 t1 = __builtin_elementwise_fma(-cy, y2v, t0);
        vf2 t2 = __builtin_elementwise_fma(-cz, z2v, t1);
        vf2 dd = t2 + cw;
        vf2 ddc = __builtin_elementwise_max(dd, zero);   // v_pk_max_f32
        const unsigned un = (unsigned)n;
        unsigned ka = (__float_as_uint(ddc.x) & 0xFFFFFC00u) | un;
        unsigned kb = (__float_as_uint(ddc.y) & 0xFFFFFC00u) | un;
        KINS4(ka, a0, a1, a2, a3);
        KINS4(kb, b0, b1, b2, b3);
    }

    // Butterfly-merge the 16 lanes' top-4 keys for both queries.
    for (int mask = 1; mask < TPQ; mask <<= 1) {
        unsigned pa0 = (unsigned)__shfl_xor((int)a0, mask, TPQ);
        unsigned pa1 = (unsigned)__shfl_xor((int)a1, mask, TPQ);
        unsigned pa2 = (unsigned)__shfl_xor((int)a2, mask, TPQ);
        unsigned pa3 = (unsigned)__shfl_xor((int)a3, mask, TPQ);
        KINS4(pa0, a0, a1, a2, a3);
        KINS4(pa1, a0, a1, a2, a3);
        KINS4(pa2, a0, a1, a2, a3);
        KINS4(pa3, a0, a1, a2, a3);
        unsigned pb0 = (unsigned)__shfl_xor((int)b0, mask, TPQ);
        unsigned pb1 = (unsigned)__shfl_xor((int)b1, mask, TPQ);
        unsigned pb2 = (unsigned)__shfl_xor((int)b2, mask, TPQ);
        unsigned pb3 = (unsigned)__shfl_xor((int)b3, mask, TPQ);
        KINS4(pb0, b0, b1, b2, b3);
        KINS4(pb1, b0, b1, b2, b3);
        KINS4(pb2, b0, b1, b2, b3);
        KINS4(pb3, b0, b1, b2, b3);
    }

    // Lanes 0 and 1 finalize queries A and B (both hold the merged keys).
    if (t < 2) {
        const unsigned c0 = t == 0 ? a0 : b0;
        const unsigned c1 = t == 0 ? a1 : b1;
        const unsigned c2 = t == 0 ? a2 : b2;
        const unsigned c3 = t == 0 ? a3 : b3;
        const float qx = t == 0 ? xa : xb;
        const float qy = t == 0 ? ya : yb;
        const float qz = t == 0 ? za : zb;
        const float qs = t == 0 ? s2a : s2b;

        int   ix[4];
        float dx[4];
#pragma unroll
        for (int k = 0; k < 4; ++k) {
            const unsigned a = k == 0 ? c0 : k == 1 ? c1 : k == 2 ? c2 : c3;
            const int n = (int)(a & 1023u);
            const float4 c = pts[n];
            // EXACT reference arithmetic: dd = (s2 - dot2) + s1
            dx[k] = __fadd_rn(__fsub_rn(qs,
                __fadd_rn(__fadd_rn(__fmul_rn(qx, c.x), __fmul_rn(qy, c.y)),
                          __fmul_rn(qz, c.z))), c.w);
            ix[k] = n;
        }
        // Exact lexicographic (d, idx) sort-4: (0,1)(2,3)(0,2)(1,3)(1,2)
#define CSWAP(a, b) do {                                            \
        bool sw = (dx[b] < dx[a]) || (dx[b] == dx[a] && ix[b] < ix[a]); \
        float td = sw ? dx[b] : dx[a]; dx[b] = sw ? dx[a] : dx[b]; dx[a] = td; \
        int   ti = sw ? ix[b] : ix[a]; ix[b] = sw ? ix[a] : ix[b]; ix[a] = ti; \
    } while (0)
        CSWAP(0, 1); CSWAP(2, 3); CSWAP(0, 2); CSWAP(1, 3); CSWAP(1, 2);
#undef CSWAP

        const float r0 = 1.0f / __fadd_rn(dx[0], 1e-8f);
        const float r1 = 1.0f / __fadd_rn(dx[1], 1e-8f);
        const float r2 = 1.0f / __fadd_rn(dx[2], 1e-8f);
        const float s  = __fadd_rn(__fadd_rn(r0, r1), r2);
        const size_t o = (size_t)b * N2_ + mA + t;
        wsi[o] = make_int4(ix[0], ix[1], ix[2], 0);
        wsw[o] = make_float4(r0 / s, r1 / s, r2 / s, 0.0f);
    }
}

// ---------------------------------------------------------------------------
// Kernel 2 (v4): gather + blend — byte-exact round-6 version (control).
// ---------------------------------------------------------------------------

__global__ __launch_bounds__(256) void blend_kernel(
    const float* __restrict__ x1, const int4* __restrict__ wsi,
    const float4* __restrict__ wsw, float* __restrict__ out) {
    __shared__ float4 L4[N1_];   // 16 KB, XOR-swizzled channel-interleaved

    int bid = blockIdx.x;
    const int mhalf = bid & 1;
    const int ct    = (bid >> 1) & 63;   // 64 channel tiles of 4
    const int b     = bid >> 7;
    const int tid   = threadIdx.x;

    // Prefetch idx/weights for all 8 m-iterations.
    const size_t wbase = (size_t)b * N2_ + (size_t)mhalf * 2048;
    int4   id[8];
    float4 w[8];
#pragma unroll
    for (int mb = 0; mb < 8; ++mb) {
        id[mb] = wsi[wbase + mb * 256 + tid];
        w[mb]  = wsw[wbase + mb * 256 + tid];
    }

    // Stage 4 channels, register-transposed into interleaved LDS.
    const float* src = x1 + ((size_t)b * C_ + (size_t)ct * 4) * N1_;
    float4 v[4];
#pragma unroll
    for (int c = 0; c < 4; ++c)
        v[c] = reinterpret_cast<const float4*>(src + (size_t)c * N1_)[tid];
#pragma unroll
    for (int e = 0; e < 4; ++e) {
        const int n = 4 * tid + e;
        L4[n ^ ((n >> 3) & 7)] = make_float4((&v[0].x)[e], (&v[1].x)[e],
                                             (&v[2].x)[e], (&v[3].x)[e]);
    }
    __syncthreads();

    const size_t obase = ((size_t)b * C_ + (size_t)ct * 4) * N2_;
#pragma unroll
    for (int mb = 0; mb < 8; ++mb) {
        const int m = mhalf * 2048 + mb * 256 + tid;
        const int na = id[mb].x, nb = id[mb].y, nc = id[mb].z;
        const float4 A  = L4[na ^ ((na >> 3) & 7)];
        const float4 Bv = L4[nb ^ ((nb >> 3) & 7)];
        const float4 Cv = L4[nc ^ ((nc >> 3) & 7)];
        const float wx = w[mb].x, wy = w[mb].y, wz = w[mb].z;
#pragma unroll
        for (int r = 0; r < 4; ++r) {
            float acc = __fadd_rn(__fadd_rn(__fmul_rn((&A.x)[r],  wx),
                                            __fmul_rn((&Bv.x)[r], wy)),
                                  __fmul_rn((&Cv.x)[r], wz));
            __builtin_nontemporal_store(acc, &out[obase + (size_t)r * N2_ + m]);
        }
    }
}

extern "C" void kernel_launch(void* const* d_in, const int* in_sizes, int n_in,
                              void* d_out, int out_size, void* d_ws, size_t ws_size,
                              hipStream_t stream) {
    const float* p1 = (const float*)d_in[0];   // [B, N1, 3]
    const float* x1 = (const float*)d_in[1];   // [B, C, N1]
    const float* p2 = (const float*)d_in[2];   // [B, N2, 3]
    float* out = (float*)d_out;                // [B, C, N2]

    int4*   wsi = (int4*)d_ws;
    float4* wsw = (float4*)((char*)d_ws + (size_t)B_ * N2_ * sizeof(int4));

    knn_kernel<<<B_ * (N2_ / QPB), 256, 0, stream>>>(p1, p2, wsi, wsw);
    blend_kernel<<<B_ * (C_ / 4) * 2, 256, 0, stream>>>(x1, wsi, wsw, out);
}

// Round 20
// 26.567 us; speedup vs baseline: 1.0146x; 1.0146x over previous
//
#include <hip/hip_runtime.h>
#include <cfloat>
#include <climits>

#define B_   8
#define N1_  1024
#define N2_  4096
#define C_   256
#define TPQ  8                  // lanes per query
#define QPB  (256 / TPQ)        // 32 queries per block

typedef float vf2 __attribute__((ext_vector_type(2)));

__device__ __forceinline__ unsigned umin_(unsigned a, unsigned b) { return a < b ? a : b; }

// Guaranteed single-op median-of-3 (u32). VOP3, all-VGPR operands.
__device__ __forceinline__ unsigned umed3_(unsigned a, unsigned b, unsigned c) {
    unsigned d;
    asm("v_med3_u32 %0, %1, %2, %3" : "=v"(d) : "v"(a), "v"(b), "v"(c));
    return d;
}

// Sorted-quad insert (invariant k0<=k1<=k2<=k3): min + 3x med3 = 4 VALU ops.
#define KINS4(k, k0, k1, k2, k3) do {                 \
    unsigned _n1 = umed3_((k), k0, k1);               \
    unsigned _n2 = umed3_((k), k1, k2);               \
    unsigned _n3 = umed3_((k), k2, k3);               \
    k0 = umin_((k), k0);  k1 = _n1;  k2 = _n2;  k3 = _n3; \
} while (0)

// ---------------------------------------------------------------------------
// Kernel 1 (v13, FINAL): 3-NN — measured-best configuration (R18, 26.66us).
// Trunc-key top-4 scan + EXACT rescue (validated R9/R14/R15/R17/R18):
//  - pair-interleaved packed-fp32 LDS; packed-FMA scan metric (3 pk_fma +
//    pk_add + pk_max per pair); key = trunc_bits(dist) | slot.
//  - TPQ=8: 32 queries/block, 1024 blocks; 3-step butterfly merge.
//  - rescue recomputes kept-4 distances in EXACT reference bit order ->
//    output bits depend only on the selected set.
// per eval: ~7.5 source VALU ops — VALU-issue-bound (R13: VALUBusy 96-100%).
// ---------------------------------------------------------------------------
__global__ __launch_bounds__(256) void knn_kernel(
    const float* __restrict__ p1, const float* __restrict__ p2,
    int4* __restrict__ wsi, float4* __restrict__ wsw) {
#pragma clang fp contract(off)
    __shared__ float4 Q[N1_ / 2];   // 8 KB
    __shared__ float4 R[N1_ / 2];   // 8 KB

    const int tid   = threadIdx.x;
    const int b     = blockIdx.x >> 7;     // 128 query-tiles per batch
    const int mtile = blockIdx.x & 127;

    // Stage coarse points, pair-interleaved, exact pre-doubling (R3 layout).
    for (int k = tid; k < N1_ / 2; k += 256) {
        const float* pa = &p1[((size_t)b * N1_ + 2 * k) * 3];
        float xa = pa[0], ya = pa[1], za = pa[2];
        float xb = pa[3], yb = pa[4], zb = pa[5];
        float sa = __fadd_rn(__fadd_rn(__fmul_rn(xa, xa), __fmul_rn(ya, ya)),
                             __fmul_rn(za, za));
        float sb = __fadd_rn(__fadd_rn(__fmul_rn(xb, xb), __fmul_rn(yb, yb)),
                             __fmul_rn(zb, zb));
        Q[k] = make_float4(xa + xa, xb + xb, ya + ya, yb + yb);
        R[k] = make_float4(za + za, zb + zb, sa, sb);
    }
    __syncthreads();

    const int q = tid >> 3;       // query within tile (0..31)
    const int t = tid & 7;        // lane within query group
    const int m = mtile * QPB + q;

    const size_t pbase = ((size_t)b * N2_ + m) * 3;
    const float x2 = p2[pbase + 0];
    const float y2 = p2[pbase + 1];
    const float z2 = p2[pbase + 2];
    const float s2 = __fadd_rn(__fadd_rn(__fmul_rn(x2, x2), __fmul_rn(y2, y2)),
                               __fmul_rn(z2, z2));

    const vf2 x2v = {x2, x2};
    const vf2 y2v = {y2, y2};
    const vf2 z2v = {z2, z2};
    const vf2 s2v = {s2, s2};
    const vf2 zero = {0.f, 0.f};

    unsigned k0 = UINT_MAX, k1 = UINT_MAX, k2 = UINT_MAX, k3 = UINT_MAX;

    // 64 pair-iterations: candidates (2k, 2k+1), k = t + 8*j.
#pragma unroll 4
    for (int j = 0; j < N1_ / (2 * TPQ); ++j) {
        const int k = t + TPQ * j;
        float4 qv = Q[k];
        float4 rv = R[k];
        vf2 qx = {qv.x, qv.y};
        vf2 qy = {qv.z, qv.w};
        vf2 rz = {rv.x, rv.y};
        vf2 rs = {rv.z, rv.w};
        // Scan metric: 3 pk_fma (neg mods free) + 1 pk_add + 1 pk_max.
        vf2 t0 = __builtin_elementwise_fma(-qx, x2v, s2v);
        vf2 t1 = __builtin_elementwise_fma(-qy, y2v, t0);
        vf2 t2 = __builtin_elementwise_fma(-rz, z2v, t1);
        vf2 dd = t2 + rs;
        vf2 ddc = __builtin_elementwise_max(dd, zero);   // v_pk_max_f32
        const unsigned un = (unsigned)(2 * k);
        unsigned ka = (__float_as_uint(ddc.x) & 0xFFFFFC00u) | un;
        unsigned kb = (__float_as_uint(ddc.y) & 0xFFFFFC00u) | (un + 1u);
        KINS4(ka, k0, k1, k2, k3);
        KINS4(kb, k0, k1, k2, k3);
    }

    // Butterfly-merge the 8 lanes' top-4 keys (u32 order, exact).
    for (int mask = 1; mask < TPQ; mask <<= 1) {
        unsigned p0 = (unsigned)__shfl_xor((int)k0, mask, TPQ);
        unsigned p1_ = (unsigned)__shfl_xor((int)k1, mask, TPQ);
        unsigned p2_ = (unsigned)__shfl_xor((int)k2, mask, TPQ);
        unsigned p3_ = (unsigned)__shfl_xor((int)k3, mask, TPQ);
        KINS4(p0,  k0, k1, k2, k3);
        KINS4(p1_, k0, k1, k2, k3);
        KINS4(p2_, k0, k1, k2, k3);
        KINS4(p3_, k0, k1, k2, k3);
    }

    if (t == 0) {
        int   ix[4];
        float dx[4];
#pragma unroll
        for (int k = 0; k < 4; ++k) {
            const unsigned a = k == 0 ? k0 : k == 1 ? k1 : k == 2 ? k2 : k3;
            const int n  = (int)(a & 1023u);
            const int kk = n >> 1;
            const int h  = n & 1;
            const float cx = h ? Q[kk].y : Q[kk].x;   // 2x
            const float cy = h ? Q[kk].w : Q[kk].z;   // 2y
            const float cz = h ? R[kk].y : R[kk].x;   // 2z
            const float cs = h ? R[kk].w : R[kk].z;   // s1
            // EXACT reference arithmetic: dd = (s2 - dot2) + s1
            dx[k] = __fadd_rn(__fsub_rn(s2,
                __fadd_rn(__fadd_rn(__fmul_rn(x2, cx), __fmul_rn(y2, cy)),
                          __fmul_rn(z2, cz))), cs);
            ix[k] = n;
        }
        // Exact lexicographic (d, idx) sort-4: (0,1)(2,3)(0,2)(1,3)(1,2)
#define CSWAP(a, b) do {                                            \
        bool sw = (dx[b] < dx[a]) || (dx[b] == dx[a] && ix[b] < ix[a]); \
        float td = sw ? dx[b] : dx[a]; dx[b] = sw ? dx[a] : dx[b]; dx[a] = td; \
        int   ti = sw ? ix[b] : ix[a]; ix[b] = sw ? ix[a] : ix[b]; ix[a] = ti; \
    } while (0)
        CSWAP(0, 1); CSWAP(2, 3); CSWAP(0, 2); CSWAP(1, 3); CSWAP(1, 2);
#undef CSWAP

        const float r0 = 1.0f / __fadd_rn(dx[0], 1e-8f);
        const float r1 = 1.0f / __fadd_rn(dx[1], 1e-8f);
        const float r2 = 1.0f / __fadd_rn(dx[2], 1e-8f);
        const float s  = __fadd_rn(__fadd_rn(r0, r1), r2);
        const size_t o = (size_t)b * N2_ + m;
        wsi[o] = make_int4(ix[0], ix[1], ix[2], 0);
        wsw[o] = make_float4(r0 / s, r1 / s, r2 / s, 0.0f);
    }
}

// ---------------------------------------------------------------------------
// Kernel 2 (v4, FINAL): gather + blend — byte-exact round-6 version.
// Channel-interleaved XOR-swizzled LDS; one ds_read_b128 per neighbor;
// full idx/w prefetch; nontemporal coalesced stores. ~7us (write floor 5.3).
// ---------------------------------------------------------------------------

__global__ __launch_bounds__(256) void blend_kernel(
    const float* __restrict__ x1, const int4* __restrict__ wsi,
    const float4* __restrict__ wsw, float* __restrict__ out) {
    __shared__ float4 L4[N1_];   // 16 KB, XOR-swizzled channel-interleaved

    int bid = blockIdx.x;
    const int mhalf = bid & 1;
    const int ct    = (bid >> 1) & 63;   // 64 channel tiles of 4
    const int b     = bid >> 7;
    const int tid   = threadIdx.x;

    // Prefetch idx/weights for all 8 m-iterations.
    const size_t wbase = (size_t)b * N2_ + (size_t)mhalf * 2048;
    int4   id[8];
    float4 w[8];
#pragma unroll
    for (int mb = 0; mb < 8; ++mb) {
        id[mb] = wsi[wbase + mb * 256 + tid];
        w[mb]  = wsw[wbase + mb * 256 + tid];
    }

    // Stage 4 channels, register-transposed into interleaved LDS.
    const float* src = x1 + ((size_t)b * C_ + (size_t)ct * 4) * N1_;
    float4 v[4];
#pragma unroll
    for (int c = 0; c < 4; ++c)
        v[c] = reinterpret_cast<const float4*>(src + (size_t)c * N1_)[tid];
#pragma unroll
    for (int e = 0; e < 4; ++e) {
        const int n = 4 * tid + e;
        L4[n ^ ((n >> 3) & 7)] = make_float4((&v[0].x)[e], (&v[1].x)[e],
                                             (&v[2].x)[e], (&v[3].x)[e]);
    }
    __syncthreads();

    const size_t obase = ((size_t)b * C_ + (size_t)ct * 4) * N2_;
#pragma unroll
    for (int mb = 0; mb < 8; ++mb) {
        const int m = mhalf * 2048 + mb * 256 + tid;
        const int na = id[mb].x, nb = id[mb].y, nc = id[mb].z;
        const float4 A  = L4[na ^ ((na >> 3) & 7)];
        const float4 Bv = L4[nb ^ ((nb >> 3) & 7)];
        const float4 Cv = L4[nc ^ ((nc >> 3) & 7)];
        const float wx = w[mb].x, wy = w[mb].y, wz = w[mb].z;
#pragma unroll
        for (int r = 0; r < 4; ++r) {
            float acc = __fadd_rn(__fadd_rn(__fmul_rn((&A.x)[r],  wx),
                                            __fmul_rn((&Bv.x)[r], wy)),
                                  __fmul_rn((&Cv.x)[r], wz));
            __builtin_nontemporal_store(acc, &out[obase + (size_t)r * N2_ + m]);
        }
    }
}

extern "C" void kernel_launch(void* const* d_in, const int* in_sizes, int n_in,
                              void* d_out, int out_size, void* d_ws, size_t ws_size,
                              hipStream_t stream) {
    const float* p1 = (const float*)d_in[0];   // [B, N1, 3]
    const float* x1 = (const float*)d_in[1];   // [B, C, N1]
    const float* p2 = (const float*)d_in[2];   // [B, N2, 3]
    float* out = (float*)d_out;                // [B, C, N2]

    int4*   wsi = (int4*)d_ws;
    float4* wsw = (float4*)((char*)d_ws + (size_t)B_ * N2_ * sizeof(int4));

    knn_kernel<<<B_ * (N2_ / QPB), 256, 0, stream>>>(p1, p2, wsi, wsw);
    blend_kernel<<<B_ * (C_ / 4) * 2, 256, 0, stream>>>(x1, wsi, wsw, out);
}